// Round 1
// baseline (358.070 us; speedup 1.0000x reference)
//
#include <hip/hip_runtime.h>
#include <cstdint>
#include <cmath>

// Problem constants
#define L_SEQ 16384
#define H_DIM 1024
#define P_DIM 512
#define NCH   256     // scan chunks
#define RCH   64      // rows per chunk (NCH*RCH == L_SEQ)

typedef short short4v __attribute__((ext_vector_type(4)));
typedef short short8v __attribute__((ext_vector_type(8)));
typedef float f32x4   __attribute__((ext_vector_type(4)));

__device__ __forceinline__ unsigned short f2bf(float f) {
    unsigned int u = __float_as_uint(f);
    u += 0x7FFFu + ((u >> 16) & 1u);
    return (unsigned short)(u >> 16);
}

// async global->LDS direct load, 16B per lane
#define GLD16(gp, lp) __builtin_amdgcn_global_load_lds( \
    (const __attribute__((address_space(1))) void*)(gp), \
    (__attribute__((address_space(3))) void*)(lp), 16, 0, 0)

// Lambda_bar^tmul = exp(tmul * step * Lam)
__device__ __forceinline__ void lam_pow(const float* Lre, const float* Lim,
                                        const float* lstep, int p, float tmul,
                                        float& ar, float& ai) {
    float step = expf(lstep[p]) * tmul;
    float lr = Lre[p], li = Lim[p];
    float mag = expf(step * lr);
    float ang = step * li;
    ar = mag * cosf(ang);
    ai = mag * sinf(ang);
}

// ---------------- prep kernels ----------------

// u (L,H) f32 -> bf16
__global__ void conv_u(const float* __restrict__ u, short* __restrict__ ub) {
    size_t i = ((size_t)blockIdx.x * 256 + threadIdx.x) * 8;
    const float4* s = (const float4*)(u + i);
    float4 v0 = s[0], v1 = s[1];
    short8v o;
    o[0] = (short)f2bf(v0.x); o[1] = (short)f2bf(v0.y);
    o[2] = (short)f2bf(v0.z); o[3] = (short)f2bf(v0.w);
    o[4] = (short)f2bf(v1.x); o[5] = (short)f2bf(v1.y);
    o[6] = (short)f2bf(v1.z); o[7] = (short)f2bf(v1.w);
    *(short8v*)&ub[i] = o;
}

// Bcat (2P=1024 rows, K=H) bf16, row p = Re(B_bar[p,:]), row p+512 = Im(B_bar[p,:])
// B_bar[p,h] = ((Lambda_bar[p]-1)/Lam[p]) * (B_ri[p,h,0] + i*B_ri[p,h,1])
__global__ void prep_B(const float* __restrict__ B_ri, short* __restrict__ Bcat,
                       const float* Lre, const float* Lim, const float* lstep) {
    int t = blockIdx.x * 256 + threadIdx.x;      // P*H/4 threads
    int p  = t >> 8;
    int h4 = (t & 255) << 2;
    float step = expf(lstep[p]);
    float lr = Lre[p], li = Lim[p];
    float mag = expf(step * lr);
    float cr = mag * cosf(step * li) - 1.0f;     // Lambda_bar - 1
    float ci = mag * sinf(step * li);
    float den = lr * lr + li * li;
    float sr = (cr * lr + ci * li) / den;        // (Lb-1)/Lam
    float si = (ci * lr - cr * li) / den;
    const float4* src = (const float4*)(B_ri + ((size_t)p * H_DIM + h4) * 2);
    float4 v0 = src[0], v1 = src[1];
    short4v re, im;
    re[0] = (short)f2bf(sr * v0.x - si * v0.y); im[0] = (short)f2bf(sr * v0.y + si * v0.x);
    re[1] = (short)f2bf(sr * v0.z - si * v0.w); im[1] = (short)f2bf(sr * v0.w + si * v0.z);
    re[2] = (short)f2bf(sr * v1.x - si * v1.y); im[2] = (short)f2bf(sr * v1.y + si * v1.x);
    re[3] = (short)f2bf(sr * v1.z - si * v1.w); im[3] = (short)f2bf(sr * v1.w + si * v1.z);
    *(short4v*)&Bcat[(size_t)p * H_DIM + h4] = re;
    *(short4v*)&Bcat[(size_t)(p + P_DIM) * H_DIM + h4] = im;
}

// Ccat (H rows, K2=2048) bf16: [2*C_re (2P) | -2*C_im (2P)]
__global__ void prep_C(const float* __restrict__ C_ri, short* __restrict__ Ccat) {
    int t = blockIdx.x * 256 + threadIdx.x;      // H*1024/4 threads
    int h  = t >> 8;
    int c4 = (t & 255) << 2;
    const float4* src = (const float4*)(C_ri + ((size_t)h * 1024 + c4) * 2);
    float4 v0 = src[0], v1 = src[1];
    short4v re, im;
    re[0] = (short)f2bf(2.0f * v0.x); im[0] = (short)f2bf(-2.0f * v0.y);
    re[1] = (short)f2bf(2.0f * v0.z); im[1] = (short)f2bf(-2.0f * v0.w);
    re[2] = (short)f2bf(2.0f * v1.x); im[2] = (short)f2bf(-2.0f * v1.y);
    re[3] = (short)f2bf(2.0f * v1.z); im[3] = (short)f2bf(-2.0f * v1.w);
    *(short4v*)&Ccat[(size_t)h * 2048 + c4] = re;
    *(short4v*)&Ccat[(size_t)h * 2048 + 1024 + c4] = im;
}

// ---------------- scan kernels ----------------
// Bu layout: (L, 1024) f32, col p = re, col p+512 = im.
// dir 0 = forward, dir 1 = backward.

__global__ void scan_phase_a(const float* __restrict__ Bu, float* __restrict__ E,
                             const float* Lre, const float* Lim, const float* lstep) {
    int chunk = blockIdx.x, dir = blockIdx.y;
    int j = threadIdx.x;                     // 0..511
    float ar, ai; lam_pow(Lre, Lim, lstep, j, 1.0f, ar, ai);
    float xr = 0.f, xi = 0.f;
    int base = chunk * RCH;
    for (int i = 0; i < RCH; ++i) {
        int row = dir ? (base + RCH - 1 - i) : (base + i);
        float br = Bu[(size_t)row * 1024 + j];
        float bi = Bu[(size_t)row * 1024 + P_DIM + j];
        float nr = fmaf(ar, xr, fmaf(-ai, xi, br));
        float ni = fmaf(ar, xi, fmaf( ai, xr, bi));
        xr = nr; xi = ni;
    }
    size_t o = ((size_t)dir * NCH + chunk) * 1024 + j;
    E[o] = xr; E[o + P_DIM] = xi;
}

__global__ void scan_carry(const float* __restrict__ E, float* __restrict__ S,
                           const float* Lre, const float* Lim, const float* lstep) {
    int dir = blockIdx.x;
    int j = threadIdx.x;
    float ar, ai; lam_pow(Lre, Lim, lstep, j, (float)RCH, ar, ai);   // Lambda_bar^RCH
    float sr = 0.f, si = 0.f;
    for (int t = 0; t < NCH; ++t) {
        int c = dir ? (NCH - 1 - t) : t;
        size_t o = ((size_t)dir * NCH + c) * 1024 + j;
        S[o] = sr; S[o + P_DIM] = si;
        float er = E[o], ei = E[o + P_DIM];
        float nr = fmaf(ar, sr, fmaf(-ai, si, er));
        float ni = fmaf(ar, si, fmaf( ai, sr, ei));
        sr = nr; si = ni;
    }
}

// XS layout (L, 2048) bf16 K-columns: [0,512) fwd_re | [512,1024) bwd_re |
// [1024,1536) fwd_im | [1536,2048) bwd_im
__global__ void scan_phase_c(const float* __restrict__ Bu, const float* __restrict__ S,
                             short* __restrict__ XS,
                             const float* Lre, const float* Lim, const float* lstep) {
    int chunk = blockIdx.x, dir = blockIdx.y;
    int j = threadIdx.x;
    float ar, ai; lam_pow(Lre, Lim, lstep, j, 1.0f, ar, ai);
    size_t so = ((size_t)dir * NCH + chunk) * 1024 + j;
    float xr = S[so], xi = S[so + P_DIM];
    int base = chunk * RCH;
    int reo = dir ? (P_DIM + j) : j;
    int imo = reo + 1024;
    for (int i = 0; i < RCH; ++i) {
        int row = dir ? (base + RCH - 1 - i) : (base + i);
        float br = Bu[(size_t)row * 1024 + j];
        float bi = Bu[(size_t)row * 1024 + P_DIM + j];
        float nr = fmaf(ar, xr, fmaf(-ai, xi, br));
        float ni = fmaf(ar, xi, fmaf( ai, xr, bi));
        xr = nr; xi = ni;
        XS[(size_t)row * 2048 + reo] = (short)f2bf(xr);
        XS[(size_t)row * 2048 + imo] = (short)f2bf(xi);
    }
}

// ---------------- GEMM (m97-structure, 128x128 tile, bf16 MFMA) ----------------
// A (M,K) bf16 row-major; Bm (N,K) bf16 row-major; Co (M,N) f32 = A @ Bm^T
// EPI: Co += Dv[col] * U[row,col]
template<int M, int N, int K, bool EPI>
__global__ __launch_bounds__(256) void gemm_bt(
    const short* __restrict__ A, const short* __restrict__ Bm, float* __restrict__ Co,
    const float* __restrict__ Dv, const float* __restrict__ U)
{
    __shared__ short As[128 * 32];
    __shared__ short Bs[128 * 32];
    int tid = threadIdx.x;
    int wave = tid >> 6, lane = tid & 63;
    constexpr int NT  = N / 128;
    constexpr int nwg = (M / 128) * NT;
    int bid = blockIdx.x;
    int wg = (bid & 7) * (nwg / 8) + (bid >> 3);   // XCD swizzle (nwg % 8 == 0)
    int m0 = (wg / NT) * 128, n0 = (wg % NT) * 128;
    int wm = (wave >> 1) * 64, wn = (wave & 1) * 64;
    int lr = lane & 15, lk = (lane >> 4) * 8;

    f32x4 zero = {0.f, 0.f, 0.f, 0.f};
    f32x4 acc[4][4];
#pragma unroll
    for (int m = 0; m < 4; ++m)
#pragma unroll
        for (int n = 0; n < 4; ++n) acc[m][n] = zero;

    const short* Ag = A  + (size_t)m0 * K;
    const short* Bg = Bm + (size_t)n0 * K;
    int e0 = tid * 8;          int r0 = e0 >> 5, c0 = e0 & 31;
    int e1 = 2048 + tid * 8;   int r1 = e1 >> 5, c1 = e1 & 31;

    for (int k0 = 0; k0 < K; k0 += 32) {
        GLD16(Ag + (size_t)r0 * K + k0 + c0, &As[e0]);
        GLD16(Ag + (size_t)r1 * K + k0 + c1, &As[e1]);
        GLD16(Bg + (size_t)r0 * K + k0 + c0, &Bs[e0]);
        GLD16(Bg + (size_t)r1 * K + k0 + c1, &Bs[e1]);
        __syncthreads();   // compiler drains vmcnt before barrier -> tiles ready
        short8v af[4], bf[4];
#pragma unroll
        for (int m = 0; m < 4; ++m)
            af[m] = *(const short8v*)&As[(wm + m * 16 + lr) * 32 + lk];
#pragma unroll
        for (int n = 0; n < 4; ++n)
            bf[n] = *(const short8v*)&Bs[(wn + n * 16 + lr) * 32 + lk];
#pragma unroll
        for (int m = 0; m < 4; ++m)
#pragma unroll
            for (int n = 0; n < 4; ++n)
                acc[m][n] = __builtin_amdgcn_mfma_f32_16x16x32_bf16(af[m], bf[n], acc[m][n], 0, 0, 0);
        __syncthreads();   // reads done before next stage overwrites
    }

    int lr4 = (lane >> 4) * 4, lc = lane & 15;
#pragma unroll
    for (int m = 0; m < 4; ++m)
#pragma unroll
        for (int n = 0; n < 4; ++n) {
            int r = m0 + wm + m * 16 + lr4;
            int c = n0 + wn + n * 16 + lc;
#pragma unroll
            for (int i = 0; i < 4; ++i) {
                float v = acc[m][n][i];
                if constexpr (EPI)
                    v = fmaf(Dv[c], U[(size_t)(r + i) * N + c], v);
                Co[(size_t)(r + i) * N + c] = v;
            }
        }
}

// ---------------- launch ----------------

extern "C" void kernel_launch(void* const* d_in, const int* in_sizes, int n_in,
                              void* d_out, int out_size, void* d_ws, size_t ws_size,
                              hipStream_t stream) {
    const float* u     = (const float*)d_in[0];   // (L,H)
    const float* Lre   = (const float*)d_in[1];   // (P,)
    const float* Lim   = (const float*)d_in[2];   // (P,)
    const float* B_ri  = (const float*)d_in[3];   // (P,H,2)
    const float* C_ri  = (const float*)d_in[4];   // (H,2P,2)
    const float* Dv    = (const float*)d_in[5];   // (H,)
    const float* lstep = (const float*)d_in[6];   // (P,)
    float* out = (float*)d_out;

    char* w = (char*)d_ws;
    short* u_bf = (short*)(w);                       // 32MB  [0,32)
    short* XS   = (short*)(w);                       // 64MB  [0,64) (after GEMM1 done)
    short* Bcat = (short*)(w + (64ull  << 20));      // 2MB
    float* Bu   = (float*)(w + (66ull  << 20));      // 64MB
    short* Ccat = (short*)(w + (130ull << 20));      // 4MB
    float* E    = (float*)(w + (134ull << 20));      // 2MB
    float* Scar = (float*)(w + (136ull << 20));      // 2MB   total 138MB

    // 1. prep
    conv_u<<<(L_SEQ * H_DIM) / (256 * 8), 256, 0, stream>>>(u, u_bf);
    prep_B<<<(P_DIM * H_DIM) / (256 * 4), 256, 0, stream>>>(B_ri, Bcat, Lre, Lim, lstep);
    prep_C<<<(H_DIM * 1024) / (256 * 4), 256, 0, stream>>>(C_ri, Ccat);

    // 2. GEMM1: Bu = u @ Bcat^T   (M=L, N=1024, K=H)
    gemm_bt<L_SEQ, 1024, H_DIM, false><<<(L_SEQ / 128) * (1024 / 128), 256, 0, stream>>>(
        u_bf, Bcat, Bu, nullptr, nullptr);

    // 3. scans
    scan_phase_a<<<dim3(NCH, 2), P_DIM, 0, stream>>>(Bu, E, Lre, Lim, lstep);
    scan_carry<<<2, P_DIM, 0, stream>>>(E, Scar, Lre, Lim, lstep);
    scan_phase_c<<<dim3(NCH, 2), P_DIM, 0, stream>>>(Bu, Scar, XS, Lre, Lim, lstep);

    // 4. GEMM2: out = XS @ Ccat^T + D*u   (M=L, N=H, K=2048)
    gemm_bt<L_SEQ, H_DIM, 2048, true><<<(L_SEQ / 128) * (H_DIM / 128), 256, 0, stream>>>(
        XS, Ccat, out, Dv, u);
}

// Round 2
// 315.454 us; speedup vs baseline: 1.1351x; 1.1351x over previous
//
#include <hip/hip_runtime.h>
#include <cstdint>
#include <cmath>

// Problem constants
#define L_SEQ 16384
#define H_DIM 1024
#define P_DIM 512
#define NCH   256     // scan chunks
#define RCH   64      // rows per chunk (NCH*RCH == L_SEQ)

typedef short short4v __attribute__((ext_vector_type(4)));
typedef short short8v __attribute__((ext_vector_type(8)));
typedef float f32x4   __attribute__((ext_vector_type(4)));

__device__ __forceinline__ unsigned short f2bf(float f) {
    unsigned int u = __float_as_uint(f);
    u += 0x7FFFu + ((u >> 16) & 1u);
    return (unsigned short)(u >> 16);
}

// async global->LDS direct load, 16B per lane
#define GLD16(gp, lp) __builtin_amdgcn_global_load_lds( \
    (const __attribute__((address_space(1))) void*)(gp), \
    (__attribute__((address_space(3))) void*)(lp), 16, 0, 0)

#define VMCNT6 asm volatile("s_waitcnt vmcnt(6)" ::: "memory")
#define VMCNT0 asm volatile("s_waitcnt vmcnt(0)" ::: "memory")
#define BARRIER do { asm volatile("" ::: "memory"); \
                     __builtin_amdgcn_s_barrier(); \
                     asm volatile("" ::: "memory"); } while (0)

// Lambda_bar^tmul = exp(tmul * step * Lam)
__device__ __forceinline__ void lam_pow(const float* Lre, const float* Lim,
                                        const float* lstep, int p, float tmul,
                                        float& ar, float& ai) {
    float step = expf(lstep[p]) * tmul;
    float lr = Lre[p], li = Lim[p];
    float mag = expf(step * lr);
    float ang = step * li;
    ar = mag * cosf(ang);
    ai = mag * sinf(ang);
}

// ---------------- prep kernels ----------------

__global__ void conv_u(const float* __restrict__ u, short* __restrict__ ub) {
    size_t i = ((size_t)blockIdx.x * 256 + threadIdx.x) * 8;
    const float4* s = (const float4*)(u + i);
    float4 v0 = s[0], v1 = s[1];
    short8v o;
    o[0] = (short)f2bf(v0.x); o[1] = (short)f2bf(v0.y);
    o[2] = (short)f2bf(v0.z); o[3] = (short)f2bf(v0.w);
    o[4] = (short)f2bf(v1.x); o[5] = (short)f2bf(v1.y);
    o[6] = (short)f2bf(v1.z); o[7] = (short)f2bf(v1.w);
    *(short8v*)&ub[i] = o;
}

// Bcat (2P=1024 rows, K=H) bf16, row p = Re(B_bar[p,:]), row p+512 = Im(B_bar[p,:])
__global__ void prep_B(const float* __restrict__ B_ri, short* __restrict__ Bcat,
                       const float* Lre, const float* Lim, const float* lstep) {
    int t = blockIdx.x * 256 + threadIdx.x;
    int p  = t >> 8;
    int h4 = (t & 255) << 2;
    float step = expf(lstep[p]);
    float lr = Lre[p], li = Lim[p];
    float mag = expf(step * lr);
    float cr = mag * cosf(step * li) - 1.0f;
    float ci = mag * sinf(step * li);
    float den = lr * lr + li * li;
    float sr = (cr * lr + ci * li) / den;
    float si = (ci * lr - cr * li) / den;
    const float4* src = (const float4*)(B_ri + ((size_t)p * H_DIM + h4) * 2);
    float4 v0 = src[0], v1 = src[1];
    short4v re, im;
    re[0] = (short)f2bf(sr * v0.x - si * v0.y); im[0] = (short)f2bf(sr * v0.y + si * v0.x);
    re[1] = (short)f2bf(sr * v0.z - si * v0.w); im[1] = (short)f2bf(sr * v0.w + si * v0.z);
    re[2] = (short)f2bf(sr * v1.x - si * v1.y); im[2] = (short)f2bf(sr * v1.y + si * v1.x);
    re[3] = (short)f2bf(sr * v1.z - si * v1.w); im[3] = (short)f2bf(sr * v1.w + si * v1.z);
    *(short4v*)&Bcat[(size_t)p * H_DIM + h4] = re;
    *(short4v*)&Bcat[(size_t)(p + P_DIM) * H_DIM + h4] = im;
}

// Ccat (H rows, K2=2048) bf16: [2*C_re (2P) | -2*C_im (2P)]
__global__ void prep_C(const float* __restrict__ C_ri, short* __restrict__ Ccat) {
    int t = blockIdx.x * 256 + threadIdx.x;
    int h  = t >> 8;
    int c4 = (t & 255) << 2;
    const float4* src = (const float4*)(C_ri + ((size_t)h * 1024 + c4) * 2);
    float4 v0 = src[0], v1 = src[1];
    short4v re, im;
    re[0] = (short)f2bf(2.0f * v0.x); im[0] = (short)f2bf(-2.0f * v0.y);
    re[1] = (short)f2bf(2.0f * v0.z); im[1] = (short)f2bf(-2.0f * v0.w);
    re[2] = (short)f2bf(2.0f * v1.x); im[2] = (short)f2bf(-2.0f * v1.y);
    re[3] = (short)f2bf(2.0f * v1.z); im[3] = (short)f2bf(-2.0f * v1.w);
    *(short4v*)&Ccat[(size_t)h * 2048 + c4] = re;
    *(short4v*)&Ccat[(size_t)h * 2048 + 1024 + c4] = im;
}

// ---------------- scan kernels ----------------

__global__ void scan_phase_a(const float* __restrict__ Bu, float* __restrict__ E,
                             const float* Lre, const float* Lim, const float* lstep) {
    int chunk = blockIdx.x, dir = blockIdx.y;
    int j = threadIdx.x;
    float ar, ai; lam_pow(Lre, Lim, lstep, j, 1.0f, ar, ai);
    float xr = 0.f, xi = 0.f;
    int base = chunk * RCH;
    for (int i = 0; i < RCH; ++i) {
        int row = dir ? (base + RCH - 1 - i) : (base + i);
        float br = Bu[(size_t)row * 1024 + j];
        float bi = Bu[(size_t)row * 1024 + P_DIM + j];
        float nr = fmaf(ar, xr, fmaf(-ai, xi, br));
        float ni = fmaf(ar, xi, fmaf( ai, xr, bi));
        xr = nr; xi = ni;
    }
    size_t o = ((size_t)dir * NCH + chunk) * 1024 + j;
    E[o] = xr; E[o + P_DIM] = xi;
}

__global__ void scan_carry(const float* __restrict__ E, float* __restrict__ S,
                           const float* Lre, const float* Lim, const float* lstep) {
    int dir = blockIdx.x;
    int j = threadIdx.x;
    float ar, ai; lam_pow(Lre, Lim, lstep, j, (float)RCH, ar, ai);
    float sr = 0.f, si = 0.f;
    for (int t = 0; t < NCH; ++t) {
        int c = dir ? (NCH - 1 - t) : t;
        size_t o = ((size_t)dir * NCH + c) * 1024 + j;
        S[o] = sr; S[o + P_DIM] = si;
        float er = E[o], ei = E[o + P_DIM];
        float nr = fmaf(ar, sr, fmaf(-ai, si, er));
        float ni = fmaf(ar, si, fmaf( ai, sr, ei));
        sr = nr; si = ni;
    }
}

__global__ void scan_phase_c(const float* __restrict__ Bu, const float* __restrict__ S,
                             short* __restrict__ XS,
                             const float* Lre, const float* Lim, const float* lstep) {
    int chunk = blockIdx.x, dir = blockIdx.y;
    int j = threadIdx.x;
    float ar, ai; lam_pow(Lre, Lim, lstep, j, 1.0f, ar, ai);
    size_t so = ((size_t)dir * NCH + chunk) * 1024 + j;
    float xr = S[so], xi = S[so + P_DIM];
    int base = chunk * RCH;
    int reo = dir ? (P_DIM + j) : j;
    int imo = reo + 1024;
    for (int i = 0; i < RCH; ++i) {
        int row = dir ? (base + RCH - 1 - i) : (base + i);
        float br = Bu[(size_t)row * 1024 + j];
        float bi = Bu[(size_t)row * 1024 + P_DIM + j];
        float nr = fmaf(ar, xr, fmaf(-ai, xi, br));
        float ni = fmaf(ar, xi, fmaf( ai, xr, bi));
        xr = nr; xi = ni;
        XS[(size_t)row * 2048 + reo] = (short)f2bf(xr);
        XS[(size_t)row * 2048 + imo] = (short)f2bf(xi);
    }
}

// ---------------- 256x256 8-phase GEMM (T2+T3+T4+T5) ----------------
// A (M,K) bf16 row-major; Bm (N,K) bf16 row-major; Co (M,N) f32 = A @ Bm^T
// K-tile = 64 split into 2 K-halves of 32. LDS: 2 bufs x {A,B} x {kh0,kh1} x 16KB.
// Tile t's 4 phases stage tile t+1's 4 halves; vmcnt(6) at P0/P2.
#define SUB(b,op,kh) (&lds[((((b)*2)+(op))*2+(kh))*8192])

#define LDB4(ptr) do { \
    bf0 = *(const short8v*)&(ptr)[roffB];        \
    bf1 = *(const short8v*)&(ptr)[roffB + 512];  \
    bf2 = *(const short8v*)&(ptr)[roffB + 1024]; \
    bf3 = *(const short8v*)&(ptr)[roffB + 1536]; } while (0)

#define LDA4(ptr, mo) do { \
    af0 = *(const short8v*)&(ptr)[roffA + ((mo)+0)*512]; \
    af1 = *(const short8v*)&(ptr)[roffA + ((mo)+1)*512]; \
    af2 = *(const short8v*)&(ptr)[roffA + ((mo)+2)*512]; \
    af3 = *(const short8v*)&(ptr)[roffA + ((mo)+3)*512]; } while (0)

#define MF4(mi, a) \
    acc[mi][0] = __builtin_amdgcn_mfma_f32_16x16x32_bf16(a, bf0, acc[mi][0], 0,0,0); \
    acc[mi][1] = __builtin_amdgcn_mfma_f32_16x16x32_bf16(a, bf1, acc[mi][1], 0,0,0); \
    acc[mi][2] = __builtin_amdgcn_mfma_f32_16x16x32_bf16(a, bf2, acc[mi][2], 0,0,0); \
    acc[mi][3] = __builtin_amdgcn_mfma_f32_16x16x32_bf16(a, bf3, acc[mi][3], 0,0,0);

#define MFMA16(mb) do { \
    __builtin_amdgcn_s_setprio(1); \
    MF4((mb)+0, af0) MF4((mb)+1, af1) MF4((mb)+2, af2) MF4((mb)+3, af3) \
    __builtin_amdgcn_s_setprio(0); } while (0)

template<int M, int N, int K, bool EPI>
__global__ __launch_bounds__(512, 2) void gemm8p(
    const short* __restrict__ A, const short* __restrict__ Bm, float* __restrict__ Co,
    const float* __restrict__ Dv, const float* __restrict__ U)
{
    __shared__ __align__(16) short lds[65536];   // 128 KiB
    constexpr int NTN = N / 256;
    constexpr int nwg = (M / 256) * NTN;
    constexpr int NT  = K / 64;
    static_assert(nwg % 8 == 0, "bijective XCD swizzle");

    int tid = threadIdx.x;
    int wave = tid >> 6, lane = tid & 63;
    int bid = blockIdx.x;
    int wg  = (bid & 7) * (nwg / 8) + (bid >> 3);
    int m0 = (wg / NTN) * 256, n0 = (wg % NTN) * 256;
    int wm = (wave >> 2) * 128, wn = (wave & 3) * 64;
    int lr = lane & 15;
    // swizzled 16B-slot index: phys = (lane>>4) ^ ((row>>1)&3); row bits 1-2 == lane bits 1-2
    int sA = (lane >> 4) ^ ((lane >> 1) & 3);
    int roffA = (wm + lr) * 32 + sA * 8;   // shorts; + m_frag*512
    int roffB = (wn + lr) * 32 + sA * 8;   // shorts; + n_frag*512

    const short* Ag = A  + (size_t)m0 * K;
    const short* Bg = Bm + (size_t)n0 * K;

    f32x4 acc[8][4];
#pragma unroll
    for (int m = 0; m < 8; ++m)
#pragma unroll
        for (int n = 0; n < 4; ++n) acc[m][n] = (f32x4){0.f, 0.f, 0.f, 0.f};

    // stage one K-half (16KB = 256 rows x 32 cols) of one operand; 2 gld/thread.
    // Global source pre-swizzled (involution within each 64B row -> still coalesced).
    auto STAGE = [&](const short* __restrict__ G, int k0, short* sb) {
#pragma unroll
        for (int j = 0; j < 2; ++j) {
            int sl  = j * 512 + tid;            // 16B slot 0..1023
            int row = sl >> 2;
            int s   = (sl & 3) ^ ((row >> 1) & 3);
            GLD16(G + (size_t)row * K + k0 + s * 8, &sb[sl * 8]);
        }
    };

    // prologue: stage tile 0 fully (4 halves, 8 gld/wave)
    STAGE(Ag, 0,  SUB(0,0,0));
    STAGE(Bg, 0,  SUB(0,1,0));
    STAGE(Ag, 32, SUB(0,0,1));
    STAGE(Bg, 32, SUB(0,1,1));

    short8v af0, af1, af2, af3, bf0, bf1, bf2, bf3;

    for (int t = 0; t < NT; ++t) {
        int b = t & 1, nb = b ^ 1;
        int tn = (t + 1 < NT) ? (t + 1) : 0;    // wrap: dummy stages keep vmcnt counts exact
        const short* Ab0 = SUB(b,0,0); const short* Bb0 = SUB(b,1,0);
        const short* Ab1 = SUB(b,0,1); const short* Bb1 = SUB(b,1,1);

        // P0: (m-half 0, k-half 0)
        STAGE(Ag, tn * 64 + 0, SUB(nb,0,0));
        VMCNT6;                 // all but last 3 stages landed -> tile t kh0 (A,B) resident
        BARRIER;
        LDB4(Bb0);
        LDA4(Ab0, 0);
        MFMA16(0);
        BARRIER;

        // P1: (m-half 1, k-half 0)
        STAGE(Bg, tn * 64 + 0, SUB(nb,1,0));
        LDA4(Ab0, 4);           // kh0 resident since P0; reads overlap other waves' P0 MFMA
        BARRIER;
        MFMA16(4);
        BARRIER;

        // P2: (m-half 0, k-half 1)
        STAGE(Ag, tn * 64 + 32, SUB(nb,0,1));
        VMCNT6;                 // tile t kh1 (A,B) resident
        BARRIER;
        LDB4(Bb1);
        LDA4(Ab1, 0);
        MFMA16(0);
        BARRIER;

        // P3: (m-half 1, k-half 1)
        STAGE(Bg, tn * 64 + 32, SUB(nb,1,1));
        LDA4(Ab1, 4);
        BARRIER;
        MFMA16(4);
        BARRIER;
    }
    VMCNT0;   // drain dummy stages before wave exit

    int lr4 = (lane >> 4) * 4;
#pragma unroll
    for (int m = 0; m < 8; ++m)
#pragma unroll
        for (int n = 0; n < 4; ++n) {
            int r = m0 + wm + m * 16 + lr4;
            int c = n0 + wn + n * 16 + lr;
#pragma unroll
            for (int i = 0; i < 4; ++i) {
                float v = acc[m][n][i];
                if constexpr (EPI)
                    v = fmaf(Dv[c], U[(size_t)(r + i) * N + c], v);
                Co[(size_t)(r + i) * N + c] = v;
            }
        }
}

// ---------------- launch ----------------

extern "C" void kernel_launch(void* const* d_in, const int* in_sizes, int n_in,
                              void* d_out, int out_size, void* d_ws, size_t ws_size,
                              hipStream_t stream) {
    const float* u     = (const float*)d_in[0];
    const float* Lre   = (const float*)d_in[1];
    const float* Lim   = (const float*)d_in[2];
    const float* B_ri  = (const float*)d_in[3];
    const float* C_ri  = (const float*)d_in[4];
    const float* Dv    = (const float*)d_in[5];
    const float* lstep = (const float*)d_in[6];
    float* out = (float*)d_out;

    char* w = (char*)d_ws;
    short* u_bf = (short*)(w);                       // 32MB  [0,32)
    short* XS   = (short*)(w);                       // 64MB  [0,64) (after GEMM1 done)
    short* Bcat = (short*)(w + (64ull  << 20));      // 2MB
    float* Bu   = (float*)(w + (66ull  << 20));      // 64MB
    short* Ccat = (short*)(w + (130ull << 20));      // 4MB
    float* E    = (float*)(w + (134ull << 20));      // 2MB
    float* Scar = (float*)(w + (136ull << 20));      // 2MB   total 138MB

    // 1. prep
    conv_u<<<(L_SEQ * H_DIM) / (256 * 8), 256, 0, stream>>>(u, u_bf);
    prep_B<<<(P_DIM * H_DIM) / (256 * 4), 256, 0, stream>>>(B_ri, Bcat, Lre, Lim, lstep);
    prep_C<<<(H_DIM * 1024) / (256 * 4), 256, 0, stream>>>(C_ri, Ccat);

    // 2. GEMM1: Bu = u @ Bcat^T   (M=L, N=1024, K=H) -> 256 wgs
    gemm8p<L_SEQ, 1024, H_DIM, false><<<(L_SEQ / 256) * (1024 / 256), 512, 0, stream>>>(
        u_bf, Bcat, Bu, nullptr, nullptr);

    // 3. scans
    scan_phase_a<<<dim3(NCH, 2), P_DIM, 0, stream>>>(Bu, E, Lre, Lim, lstep);
    scan_carry<<<2, P_DIM, 0, stream>>>(E, Scar, Lre, Lim, lstep);
    scan_phase_c<<<dim3(NCH, 2), P_DIM, 0, stream>>>(Bu, Scar, XS, Lre, Lim, lstep);

    // 4. GEMM2: out = XS @ Ccat^T + D*u   (M=L, N=H, K=2048) -> 256 wgs
    gemm8p<L_SEQ, H_DIM, 2048, true><<<(L_SEQ / 256) * (H_DIM / 256), 512, 0, stream>>>(
        XS, Ccat, out, Dv, u);
}

// Round 4
// 302.287 us; speedup vs baseline: 1.1845x; 1.0436x over previous
//
#include <hip/hip_runtime.h>
#include <cstdint>
#include <cmath>

// Problem constants
#define L_SEQ 16384
#define H_DIM 1024
#define P_DIM 512
#define NCH   256     // scan chunks
#define RCH   64      // rows per chunk (NCH*RCH == L_SEQ)

typedef short short4v __attribute__((ext_vector_type(4)));
typedef short short8v __attribute__((ext_vector_type(8)));
typedef float f32x4   __attribute__((ext_vector_type(4)));

__device__ __forceinline__ unsigned short f2bf(float f) {
    unsigned int u = __float_as_uint(f);
    u += 0x7FFFu + ((u >> 16) & 1u);
    return (unsigned short)(u >> 16);
}

// async global->LDS direct load, 16B per lane
#define GLD16(gp, lp) __builtin_amdgcn_global_load_lds( \
    (const __attribute__((address_space(1))) void*)(gp), \
    (__attribute__((address_space(3))) void*)(lp), 16, 0, 0)

#define VMCNT6 asm volatile("s_waitcnt vmcnt(6)" ::: "memory")
#define VMCNT0 asm volatile("s_waitcnt vmcnt(0)" ::: "memory")
#define BARRIER do { asm volatile("" ::: "memory"); \
                     __builtin_amdgcn_s_barrier(); \
                     asm volatile("" ::: "memory"); } while (0)

// Lambda_bar^tmul = exp(tmul * step * Lam)
__device__ __forceinline__ void lam_pow(const float* Lre, const float* Lim,
                                        const float* lstep, int p, float tmul,
                                        float& ar, float& ai) {
    float step = expf(lstep[p]) * tmul;
    float lr = Lre[p], li = Lim[p];
    float mag = expf(step * lr);
    float ang = step * li;
    ar = mag * cosf(ang);
    ai = mag * sinf(ang);
}

// ---------------- prep kernels ----------------

__global__ void conv_u(const float* __restrict__ u, short* __restrict__ ub) {
    size_t i = ((size_t)blockIdx.x * 256 + threadIdx.x) * 8;
    const float4* s = (const float4*)(u + i);
    float4 v0 = s[0], v1 = s[1];
    short8v o;
    o[0] = (short)f2bf(v0.x); o[1] = (short)f2bf(v0.y);
    o[2] = (short)f2bf(v0.z); o[3] = (short)f2bf(v0.w);
    o[4] = (short)f2bf(v1.x); o[5] = (short)f2bf(v1.y);
    o[6] = (short)f2bf(v1.z); o[7] = (short)f2bf(v1.w);
    *(short8v*)&ub[i] = o;
}

// Bcat (2P=1024 rows, K=H) bf16, row p = Re(B_bar[p,:]), row p+512 = Im(B_bar[p,:])
__global__ void prep_B(const float* __restrict__ B_ri, short* __restrict__ Bcat,
                       const float* Lre, const float* Lim, const float* lstep) {
    int t = blockIdx.x * 256 + threadIdx.x;
    int p  = t >> 8;
    int h4 = (t & 255) << 2;
    float step = expf(lstep[p]);
    float lr = Lre[p], li = Lim[p];
    float mag = expf(step * lr);
    float cr = mag * cosf(step * li) - 1.0f;
    float ci = mag * sinf(step * li);
    float den = lr * lr + li * li;
    float sr = (cr * lr + ci * li) / den;
    float si = (ci * lr - cr * li) / den;
    const float4* src = (const float4*)(B_ri + ((size_t)p * H_DIM + h4) * 2);
    float4 v0 = src[0], v1 = src[1];
    short4v re, im;
    re[0] = (short)f2bf(sr * v0.x - si * v0.y); im[0] = (short)f2bf(sr * v0.y + si * v0.x);
    re[1] = (short)f2bf(sr * v0.z - si * v0.w); im[1] = (short)f2bf(sr * v0.w + si * v0.z);
    re[2] = (short)f2bf(sr * v1.x - si * v1.y); im[2] = (short)f2bf(sr * v1.y + si * v1.x);
    re[3] = (short)f2bf(sr * v1.z - si * v1.w); im[3] = (short)f2bf(sr * v1.w + si * v1.z);
    *(short4v*)&Bcat[(size_t)p * H_DIM + h4] = re;
    *(short4v*)&Bcat[(size_t)(p + P_DIM) * H_DIM + h4] = im;
}

// Ccat (H rows, K2=2048) bf16: [2*C_re (2P) | -2*C_im (2P)]
__global__ void prep_C(const float* __restrict__ C_ri, short* __restrict__ Ccat) {
    int t = blockIdx.x * 256 + threadIdx.x;
    int h  = t >> 8;
    int c4 = (t & 255) << 2;
    const float4* src = (const float4*)(C_ri + ((size_t)h * 1024 + c4) * 2);
    float4 v0 = src[0], v1 = src[1];
    short4v re, im;
    re[0] = (short)f2bf(2.0f * v0.x); im[0] = (short)f2bf(-2.0f * v0.y);
    re[1] = (short)f2bf(2.0f * v0.z); im[1] = (short)f2bf(-2.0f * v0.w);
    re[2] = (short)f2bf(2.0f * v1.x); im[2] = (short)f2bf(-2.0f * v1.y);
    re[3] = (short)f2bf(2.0f * v1.z); im[3] = (short)f2bf(-2.0f * v1.w);
    *(short4v*)&Ccat[(size_t)h * 2048 + c4] = re;
    *(short4v*)&Ccat[(size_t)h * 2048 + 1024 + c4] = im;
}

// ---------------- scan kernels ----------------
// Bu layout: (L, 1024) f32, col p = re, col p+512 = im. dir 0 fwd, 1 bwd.

__global__ void scan_phase_a(const float* __restrict__ Bu, float* __restrict__ E,
                             const float* Lre, const float* Lim, const float* lstep) {
    int chunk = blockIdx.x, dir = blockIdx.y;
    int j = threadIdx.x;
    float ar, ai; lam_pow(Lre, Lim, lstep, j, 1.0f, ar, ai);
    float xr = 0.f, xi = 0.f;
    int base = chunk * RCH;
    for (int i = 0; i < RCH; ++i) {
        int row = dir ? (base + RCH - 1 - i) : (base + i);
        float br = Bu[(size_t)row * 1024 + j];
        float bi = Bu[(size_t)row * 1024 + P_DIM + j];
        float nr = fmaf(ar, xr, fmaf(-ai, xi, br));
        float ni = fmaf(ar, xi, fmaf( ai, xr, bi));
        xr = nr; xi = ni;
    }
    size_t o = ((size_t)dir * NCH + chunk) * 1024 + j;
    E[o] = xr; E[o + P_DIM] = xi;
}

// 3-level carry: segment aggregates (16 chunks/seg) -> mid scan over 16 segs -> expand.
__global__ void carry_seg(const float* __restrict__ E, float* __restrict__ G,
                          const float* Lre, const float* Lim, const float* lstep) {
    int s = blockIdx.x, dir = blockIdx.y, j = threadIdx.x;
    float ar, ai; lam_pow(Lre, Lim, lstep, j, (float)RCH, ar, ai);
    float gr = 0.f, gi = 0.f;
    for (int t = 0; t < 16; ++t) {
        int pos = s * 16 + t;
        int c = dir ? (NCH - 1 - pos) : pos;
        size_t o = ((size_t)dir * NCH + c) * 1024 + j;
        float er = E[o], ei = E[o + P_DIM];
        float nr = fmaf(ar, gr, fmaf(-ai, gi, er));
        float ni = fmaf(ar, gi, fmaf( ai, gr, ei));
        gr = nr; gi = ni;
    }
    size_t o = ((size_t)dir * 16 + s) * 1024 + j;
    G[o] = gr; G[o + P_DIM] = gi;
}

__global__ void carry_mid(const float* __restrict__ G, float* __restrict__ T,
                          const float* Lre, const float* Lim, const float* lstep) {
    int dir = blockIdx.x, j = threadIdx.x;
    float ar, ai; lam_pow(Lre, Lim, lstep, j, (float)(RCH * 16), ar, ai);
    float tr = 0.f, ti = 0.f;
    for (int s = 0; s < 16; ++s) {
        size_t o = ((size_t)dir * 16 + s) * 1024 + j;
        T[o] = tr; T[o + P_DIM] = ti;
        float gr = G[o], gi = G[o + P_DIM];
        float nr = fmaf(ar, tr, fmaf(-ai, ti, gr));
        float ni = fmaf(ar, ti, fmaf( ai, tr, gi));
        tr = nr; ti = ni;
    }
}

__global__ void carry_exp(const float* __restrict__ E, const float* __restrict__ T,
                          float* __restrict__ S,
                          const float* Lre, const float* Lim, const float* lstep) {
    int s = blockIdx.x, dir = blockIdx.y, j = threadIdx.x;
    float ar, ai; lam_pow(Lre, Lim, lstep, j, (float)RCH, ar, ai);
    size_t ot = ((size_t)dir * 16 + s) * 1024 + j;
    float xr = T[ot], xi = T[ot + P_DIM];
    for (int t = 0; t < 16; ++t) {
        int pos = s * 16 + t;
        int c = dir ? (NCH - 1 - pos) : pos;
        size_t o = ((size_t)dir * NCH + c) * 1024 + j;
        S[o] = xr; S[o + P_DIM] = xi;
        float er = E[o], ei = E[o + P_DIM];
        float nr = fmaf(ar, xr, fmaf(-ai, xi, er));
        float ni = fmaf(ar, xi, fmaf( ai, xr, ei));
        xr = nr; xi = ni;
    }
}

// XS layout (L, 2048) bf16: [fwd_re | bwd_re | fwd_im | bwd_im]
__global__ void scan_phase_c(const float* __restrict__ Bu, const float* __restrict__ S,
                             short* __restrict__ XS,
                             const float* Lre, const float* Lim, const float* lstep) {
    int chunk = blockIdx.x, dir = blockIdx.y;
    int j = threadIdx.x;
    float ar, ai; lam_pow(Lre, Lim, lstep, j, 1.0f, ar, ai);
    size_t so = ((size_t)dir * NCH + chunk) * 1024 + j;
    float xr = S[so], xi = S[so + P_DIM];
    int base = chunk * RCH;
    int reo = dir ? (P_DIM + j) : j;
    int imo = reo + 1024;
    for (int i = 0; i < RCH; ++i) {
        int row = dir ? (base + RCH - 1 - i) : (base + i);
        float br = Bu[(size_t)row * 1024 + j];
        float bi = Bu[(size_t)row * 1024 + P_DIM + j];
        float nr = fmaf(ar, xr, fmaf(-ai, xi, br));
        float ni = fmaf(ar, xi, fmaf( ai, xr, bi));
        xr = nr; xi = ni;
        XS[(size_t)row * 2048 + reo] = (short)f2bf(xr);
        XS[(size_t)row * 2048 + imo] = (short)f2bf(xi);
    }
}

// ---------------- 256x256 GEMM, 2 barrier-regions per K-tile ----------------
// A (M,K) bf16 rm; Bm (N,K) bf16 rm; Co = A @ Bm^T (+ EPI: Dv[c]*U[r,c])
// LDS: 2 bufs x {A,B} x {kh0,kh1} x 16KB. All reads of tile t hit buf b;
// all 4 stages of tile t+1 write buf nb. vmcnt(6) before each region's barrier
// guarantees the k-half about to be read is fully resident (all waves).
#define SUB(b,op,kh) (&lds[((((b)*2)+(op))*2+(kh))*8192])

#define LDB(base) do { const short* _p = (base); \
    b0 = *(const short8v*)&_p[roffB];        b1 = *(const short8v*)&_p[roffB + 512]; \
    b2 = *(const short8v*)&_p[roffB + 1024]; b3 = *(const short8v*)&_p[roffB + 1536]; } while (0)
#define LDAL(base) do { const short* _p = (base); \
    aL0 = *(const short8v*)&_p[roffA];        aL1 = *(const short8v*)&_p[roffA + 512]; \
    aL2 = *(const short8v*)&_p[roffA + 1024]; aL3 = *(const short8v*)&_p[roffA + 1536]; } while (0)
#define LDAH(base) do { const short* _p = (base); \
    aH0 = *(const short8v*)&_p[roffA + 2048]; aH1 = *(const short8v*)&_p[roffA + 2560]; \
    aH2 = *(const short8v*)&_p[roffA + 3072]; aH3 = *(const short8v*)&_p[roffA + 3584]; } while (0)

#define MF4(mi, a) \
    acc[mi][0] = __builtin_amdgcn_mfma_f32_16x16x32_bf16(a, b0, acc[mi][0], 0,0,0); \
    acc[mi][1] = __builtin_amdgcn_mfma_f32_16x16x32_bf16(a, b1, acc[mi][1], 0,0,0); \
    acc[mi][2] = __builtin_amdgcn_mfma_f32_16x16x32_bf16(a, b2, acc[mi][2], 0,0,0); \
    acc[mi][3] = __builtin_amdgcn_mfma_f32_16x16x32_bf16(a, b3, acc[mi][3], 0,0,0);

#define MFMA16L do { __builtin_amdgcn_s_setprio(1); \
    MF4(0, aL0) MF4(1, aL1) MF4(2, aL2) MF4(3, aL3) \
    __builtin_amdgcn_s_setprio(0); } while (0)
#define MFMA16H do { __builtin_amdgcn_s_setprio(1); \
    MF4(4, aH0) MF4(5, aH1) MF4(6, aH2) MF4(7, aH3) \
    __builtin_amdgcn_s_setprio(0); } while (0)

template<int M, int N, int K, bool EPI>
__global__ __launch_bounds__(512, 2) void gemm2r(
    const short* __restrict__ A, const short* __restrict__ Bm, float* __restrict__ Co,
    const float* __restrict__ Dv, const float* __restrict__ U)
{
    __shared__ __align__(16) short lds[65536];   // 128 KiB
    constexpr int NTN = N / 256;
    constexpr int nwg = (M / 256) * NTN;
    constexpr int NT  = K / 64;
    static_assert(nwg % 8 == 0, "bijective XCD swizzle");

    int tid = threadIdx.x;
    int wave = tid >> 6, lane = tid & 63;
    int bid = blockIdx.x;
    int wg  = (bid & 7) * (nwg / 8) + (bid >> 3);
    int m0 = (wg / NTN) * 256, n0 = (wg % NTN) * 256;
    int wm = (wave >> 2) * 128, wn = (wave & 3) * 64;
    int lr = lane & 15;
    // bank swizzle: 16B phys slot = logical ^ ((row>>1)&3); row bits 1-2 == lane bits 1-2
    int sA = (lane >> 4) ^ ((lane >> 1) & 3);
    int roffA = (wm + lr) * 32 + sA * 8;
    int roffB = (wn + lr) * 32 + sA * 8;

    const short* Ag = A  + (size_t)m0 * K;
    const short* Bg = Bm + (size_t)n0 * K;

    // precomputed per-thread stage addresses (pre-swizzled global source, linear LDS dest)
    int sl0 = tid, sl1 = 512 + tid;
    size_t ga0 = (size_t)(sl0 >> 2) * K + (size_t)((((sl0 & 3) ^ ((sl0 >> 3) & 3))) * 8);
    size_t ga1 = (size_t)(sl1 >> 2) * K + (size_t)((((sl1 & 3) ^ ((sl1 >> 3) & 3))) * 8);
    int ld0 = sl0 * 8, ld1 = sl1 * 8;

    f32x4 acc[8][4];
#pragma unroll
    for (int m = 0; m < 8; ++m)
#pragma unroll
        for (int n = 0; n < 4; ++n) acc[m][n] = (f32x4){0.f, 0.f, 0.f, 0.f};

#define STAGE(G, k0, sb) do { short* _s = (sb); \
        GLD16((G) + ga0 + (k0), &_s[ld0]); \
        GLD16((G) + ga1 + (k0), &_s[ld1]); } while (0)

    // prologue: tile 0, 4 half-stages (8 gld/thread-pair pattern)
    STAGE(Ag, 0,  SUB(0,0,0));
    STAGE(Bg, 0,  SUB(0,1,0));
    STAGE(Ag, 32, SUB(0,0,1));
    STAGE(Bg, 32, SUB(0,1,1));

    short8v aL0, aL1, aL2, aL3, aH0, aH1, aH2, aH3, b0, b1, b2, b3;

    for (int t = 0; t < NT; ++t) {
        int b = t & 1, nb = b ^ 1;
        int kn = ((t + 1 < NT) ? (t + 1) : 0) * 64;   // wrap: dummy stages keep counts exact
        const short* Ab0 = SUB(b,0,0); const short* Ab1 = SUB(b,0,1);
        const short* Bb0 = SUB(b,1,0); const short* Bb1 = SUB(b,1,1);

        // ---- Region 1: k-half 0 ----
        STAGE(Ag, kn, SUB(nb,0,0));
        VMCNT6;                  // own S(A,kh0),S(B,kh0) of tile t landed
        BARRIER;                 // -> all waves' portions landed; prev reads of nb complete
        LDB(Bb0); LDAL(Ab0); LDAH(Ab0);   // 12 ds_read_b128; MFMA16L waits lgkmcnt(4)
        MFMA16L;                 // aH reads drain under MFMA
        STAGE(Bg, kn, SUB(nb,1,0));
        MFMA16H;

        // ---- Region 2: k-half 1 ----
        STAGE(Ag, kn + 32, SUB(nb,0,1));
        VMCNT6;                  // S(A,kh1),S(B,kh1) of tile t landed
        BARRIER;
        LDB(Bb1); LDAL(Ab1); LDAH(Ab1);
        MFMA16L;
        STAGE(Bg, kn + 32, SUB(nb,1,1));
        MFMA16H;
    }
    VMCNT0;   // drain dummy tail stages

    int lr4 = (lane >> 4) * 4;
#pragma unroll
    for (int m = 0; m < 8; ++m)
#pragma unroll
        for (int n = 0; n < 4; ++n) {
            int r = m0 + wm + m * 16 + lr4;
            int c = n0 + wn + n * 16 + lr;
#pragma unroll
            for (int i = 0; i < 4; ++i) {
                float v = acc[m][n][i];
                if constexpr (EPI)
                    v = fmaf(Dv[c], U[(size_t)(r + i) * N + c], v);
                Co[(size_t)(r + i) * N + c] = v;
            }
        }
#undef STAGE
}

// ---------------- launch ----------------

extern "C" void kernel_launch(void* const* d_in, const int* in_sizes, int n_in,
                              void* d_out, int out_size, void* d_ws, size_t ws_size,
                              hipStream_t stream) {
    const float* u     = (const float*)d_in[0];
    const float* Lre   = (const float*)d_in[1];
    const float* Lim   = (const float*)d_in[2];
    const float* B_ri  = (const float*)d_in[3];
    const float* C_ri  = (const float*)d_in[4];
    const float* Dv    = (const float*)d_in[5];
    const float* lstep = (const float*)d_in[6];
    float* out = (float*)d_out;

    char* w = (char*)d_ws;
    short* u_bf = (short*)(w);                       // 32MB  [0,32)
    short* XS   = (short*)(w);                       // 64MB  [0,64) (after GEMM1 done)
    float* Gseg = (float*)(w + (33ull  << 20));      // 128KB (inside XS region, dead before phase_c)
    float* Tseg = (float*)(w + (34ull  << 20));      // 128KB (ditto)
    short* Bcat = (short*)(w + (64ull  << 20));      // 2MB
    float* Bu   = (float*)(w + (66ull  << 20));      // 64MB
    short* Ccat = (short*)(w + (130ull << 20));      // 4MB
    float* E    = (float*)(w + (134ull << 20));      // 2MB
    float* Scar = (float*)(w + (136ull << 20));      // 2MB   total 138MB

    // 1. prep
    conv_u<<<(L_SEQ * H_DIM) / (256 * 8), 256, 0, stream>>>(u, u_bf);
    prep_B<<<(P_DIM * H_DIM) / (256 * 4), 256, 0, stream>>>(B_ri, Bcat, Lre, Lim, lstep);
    prep_C<<<(H_DIM * 1024) / (256 * 4), 256, 0, stream>>>(C_ri, Ccat);

    // 2. GEMM1: Bu = u @ Bcat^T   (M=L, N=1024, K=H) -> 256 wgs
    gemm2r<L_SEQ, 1024, H_DIM, false><<<(L_SEQ / 256) * (1024 / 256), 512, 0, stream>>>(
        u_bf, Bcat, Bu, nullptr, nullptr);

    // 3. scans
    scan_phase_a<<<dim3(NCH, 2), P_DIM, 0, stream>>>(Bu, E, Lre, Lim, lstep);
    carry_seg<<<dim3(16, 2), P_DIM, 0, stream>>>(E, Gseg, Lre, Lim, lstep);
    carry_mid<<<2, P_DIM, 0, stream>>>(Gseg, Tseg, Lre, Lim, lstep);
    carry_exp<<<dim3(16, 2), P_DIM, 0, stream>>>(E, Tseg, Scar, Lre, Lim, lstep);
    scan_phase_c<<<dim3(NCH, 2), P_DIM, 0, stream>>>(Bu, Scar, XS, Lre, Lim, lstep);

    // 4. GEMM2: out = XS @ Ccat^T + D*u   (M=L, N=H, K=2048) -> 256 wgs
    gemm2r<L_SEQ, H_DIM, 2048, true><<<(L_SEQ / 256) * (H_DIM / 256), 512, 0, stream>>>(
        XS, Ccat, out, Dv, u);
}

// Round 5
// 279.413 us; speedup vs baseline: 1.2815x; 1.0819x over previous
//
#include <hip/hip_runtime.h>
#include <cstdint>
#include <cmath>

// Problem constants
#define L_SEQ 16384
#define H_DIM 1024
#define P_DIM 512
#define NCH   256     // scan chunks
#define RCH   64      // rows per chunk (NCH*RCH == L_SEQ)

typedef short short4v __attribute__((ext_vector_type(4)));
typedef short short8v __attribute__((ext_vector_type(8)));
typedef float f32x4   __attribute__((ext_vector_type(4)));

__device__ __forceinline__ unsigned short f2bf(float f) {
    unsigned int u = __float_as_uint(f);
    u += 0x7FFFu + ((u >> 16) & 1u);
    return (unsigned short)(u >> 16);
}
__device__ __forceinline__ float bf2f(short s) {
    unsigned int u = ((unsigned int)(unsigned short)s) << 16;
    return __uint_as_float(u);
}

// async global->LDS direct load, 16B per lane
#define GLD16(gp, lp) __builtin_amdgcn_global_load_lds( \
    (const __attribute__((address_space(1))) void*)(gp), \
    (__attribute__((address_space(3))) void*)(lp), 16, 0, 0)

#define VMCNT4 asm volatile("s_waitcnt vmcnt(4)" ::: "memory")
#define VMCNT0 asm volatile("s_waitcnt vmcnt(0)" ::: "memory")
#define LGKM0  do { asm volatile("s_waitcnt lgkmcnt(0)" ::: "memory"); \
                    __builtin_amdgcn_sched_barrier(0); } while (0)
#define BARRIER do { asm volatile("" ::: "memory"); \
                     __builtin_amdgcn_s_barrier(); \
                     asm volatile("" ::: "memory"); } while (0)

// Lambda_bar^tmul = exp(tmul * step * Lam)
__device__ __forceinline__ void lam_pow(const float* Lre, const float* Lim,
                                        const float* lstep, int p, float tmul,
                                        float& ar, float& ai) {
    float step = expf(lstep[p]) * tmul;
    float lr = Lre[p], li = Lim[p];
    float mag = expf(step * lr);
    float ang = step * li;
    ar = mag * cosf(ang);
    ai = mag * sinf(ang);
}

// ---------------- prep kernels ----------------

__global__ void conv_u(const float* __restrict__ u, short* __restrict__ ub) {
    size_t i = ((size_t)blockIdx.x * 256 + threadIdx.x) * 8;
    const float4* s = (const float4*)(u + i);
    float4 v0 = s[0], v1 = s[1];
    short8v o;
    o[0] = (short)f2bf(v0.x); o[1] = (short)f2bf(v0.y);
    o[2] = (short)f2bf(v0.z); o[3] = (short)f2bf(v0.w);
    o[4] = (short)f2bf(v1.x); o[5] = (short)f2bf(v1.y);
    o[6] = (short)f2bf(v1.z); o[7] = (short)f2bf(v1.w);
    *(short8v*)&ub[i] = o;
}

// Bcat (2P=1024 rows, K=H) bf16, row p = Re(B_bar[p,:]), row p+512 = Im(B_bar[p,:])
__global__ void prep_B(const float* __restrict__ B_ri, short* __restrict__ Bcat,
                       const float* Lre, const float* Lim, const float* lstep) {
    int t = blockIdx.x * 256 + threadIdx.x;
    int p  = t >> 8;
    int h4 = (t & 255) << 2;
    float step = expf(lstep[p]);
    float lr = Lre[p], li = Lim[p];
    float mag = expf(step * lr);
    float cr = mag * cosf(step * li) - 1.0f;
    float ci = mag * sinf(step * li);
    float den = lr * lr + li * li;
    float sr = (cr * lr + ci * li) / den;
    float si = (ci * lr - cr * li) / den;
    const float4* src = (const float4*)(B_ri + ((size_t)p * H_DIM + h4) * 2);
    float4 v0 = src[0], v1 = src[1];
    short4v re, im;
    re[0] = (short)f2bf(sr * v0.x - si * v0.y); im[0] = (short)f2bf(sr * v0.y + si * v0.x);
    re[1] = (short)f2bf(sr * v0.z - si * v0.w); im[1] = (short)f2bf(sr * v0.w + si * v0.z);
    re[2] = (short)f2bf(sr * v1.x - si * v1.y); im[2] = (short)f2bf(sr * v1.y + si * v1.x);
    re[3] = (short)f2bf(sr * v1.z - si * v1.w); im[3] = (short)f2bf(sr * v1.w + si * v1.z);
    *(short4v*)&Bcat[(size_t)p * H_DIM + h4] = re;
    *(short4v*)&Bcat[(size_t)(p + P_DIM) * H_DIM + h4] = im;
}

// Ccat (H rows, K2=2048) bf16: [2*C_re (2P) | -2*C_im (2P)]
__global__ void prep_C(const float* __restrict__ C_ri, short* __restrict__ Ccat) {
    int t = blockIdx.x * 256 + threadIdx.x;
    int h  = t >> 8;
    int c4 = (t & 255) << 2;
    const float4* src = (const float4*)(C_ri + ((size_t)h * 1024 + c4) * 2);
    float4 v0 = src[0], v1 = src[1];
    short4v re, im;
    re[0] = (short)f2bf(2.0f * v0.x); im[0] = (short)f2bf(-2.0f * v0.y);
    re[1] = (short)f2bf(2.0f * v0.z); im[1] = (short)f2bf(-2.0f * v0.w);
    re[2] = (short)f2bf(2.0f * v1.x); im[2] = (short)f2bf(-2.0f * v1.y);
    re[3] = (short)f2bf(2.0f * v1.z); im[3] = (short)f2bf(-2.0f * v1.w);
    *(short4v*)&Ccat[(size_t)h * 2048 + c4] = re;
    *(short4v*)&Ccat[(size_t)h * 2048 + 1024 + c4] = im;
}

// ---------------- scan kernels ----------------
// Bu layout: (L, 1024) bf16, col p = re, col p+512 = im.

// fused fwd+bwd chunk aggregates, single read pass.
// fwd agg (dir0): Horner ascending. bwd agg (dir1): sum w_i*bu_i with w=Lam^i ascending.
__global__ void scan_phase_a(const short* __restrict__ Bu, float* __restrict__ E,
                             const float* Lre, const float* Lim, const float* lstep) {
    int chunk = blockIdx.x;
    int j = threadIdx.x;
    float ar, ai; lam_pow(Lre, Lim, lstep, j, 1.0f, ar, ai);
    float fr = 0.f, fi = 0.f;
    float gr = 0.f, gi = 0.f;
    float wr = 1.f, wi = 0.f;
    int base = chunk * RCH;
    for (int i = 0; i < RCH; ++i) {
        int row = base + i;
        float xr = bf2f(Bu[(size_t)row * 1024 + j]);
        float xi = bf2f(Bu[(size_t)row * 1024 + P_DIM + j]);
        float nfr = fmaf(ar, fr, fmaf(-ai, fi, xr));
        float nfi = fmaf(ar, fi, fmaf( ai, fr, xi));
        fr = nfr; fi = nfi;
        gr = fmaf(wr, xr, fmaf(-wi, xi, gr));
        gi = fmaf(wr, xi, fmaf( wi, xr, gi));
        float nwr = wr * ar - wi * ai;
        float nwi = wr * ai + wi * ar;
        wr = nwr; wi = nwi;
    }
    size_t of = ((size_t)0 * NCH + chunk) * 1024 + j;
    size_t ob = ((size_t)1 * NCH + chunk) * 1024 + j;
    E[of] = fr; E[of + P_DIM] = fi;
    E[ob] = gr; E[ob + P_DIM] = gi;
}

// 3-level carry: segment aggregates (16 chunks/seg) -> mid scan over 16 segs -> expand.
__global__ void carry_seg(const float* __restrict__ E, float* __restrict__ G,
                          const float* Lre, const float* Lim, const float* lstep) {
    int s = blockIdx.x, dir = blockIdx.y, j = threadIdx.x;
    float ar, ai; lam_pow(Lre, Lim, lstep, j, (float)RCH, ar, ai);
    float gr = 0.f, gi = 0.f;
    for (int t = 0; t < 16; ++t) {
        int pos = s * 16 + t;
        int c = dir ? (NCH - 1 - pos) : pos;
        size_t o = ((size_t)dir * NCH + c) * 1024 + j;
        float er = E[o], ei = E[o + P_DIM];
        float nr = fmaf(ar, gr, fmaf(-ai, gi, er));
        float ni = fmaf(ar, gi, fmaf( ai, gr, ei));
        gr = nr; gi = ni;
    }
    size_t o = ((size_t)dir * 16 + s) * 1024 + j;
    G[o] = gr; G[o + P_DIM] = gi;
}

__global__ void carry_mid(const float* __restrict__ G, float* __restrict__ T,
                          const float* Lre, const float* Lim, const float* lstep) {
    int dir = blockIdx.x, j = threadIdx.x;
    float ar, ai; lam_pow(Lre, Lim, lstep, j, (float)(RCH * 16), ar, ai);
    float tr = 0.f, ti = 0.f;
    for (int s = 0; s < 16; ++s) {
        size_t o = ((size_t)dir * 16 + s) * 1024 + j;
        T[o] = tr; T[o + P_DIM] = ti;
        float gr = G[o], gi = G[o + P_DIM];
        float nr = fmaf(ar, tr, fmaf(-ai, ti, gr));
        float ni = fmaf(ar, ti, fmaf( ai, tr, gi));
        tr = nr; ti = ni;
    }
}

__global__ void carry_exp(const float* __restrict__ E, const float* __restrict__ T,
                          float* __restrict__ S,
                          const float* Lre, const float* Lim, const float* lstep) {
    int s = blockIdx.x, dir = blockIdx.y, j = threadIdx.x;
    float ar, ai; lam_pow(Lre, Lim, lstep, j, (float)RCH, ar, ai);
    size_t ot = ((size_t)dir * 16 + s) * 1024 + j;
    float xr = T[ot], xi = T[ot + P_DIM];
    for (int t = 0; t < 16; ++t) {
        int pos = s * 16 + t;
        int c = dir ? (NCH - 1 - pos) : pos;
        size_t o = ((size_t)dir * NCH + c) * 1024 + j;
        S[o] = xr; S[o + P_DIM] = xi;
        float er = E[o], ei = E[o + P_DIM];
        float nr = fmaf(ar, xr, fmaf(-ai, xi, er));
        float ni = fmaf(ar, xi, fmaf( ai, xr, ei));
        xr = nr; xi = ni;
    }
}

// XS layout (L, 2048) bf16: [fwd_re | bwd_re | fwd_im | bwd_im]
__global__ void scan_phase_c(const short* __restrict__ Bu, const float* __restrict__ S,
                             short* __restrict__ XS,
                             const float* Lre, const float* Lim, const float* lstep) {
    int chunk = blockIdx.x, dir = blockIdx.y;
    int j = threadIdx.x;
    float ar, ai; lam_pow(Lre, Lim, lstep, j, 1.0f, ar, ai);
    size_t so = ((size_t)dir * NCH + chunk) * 1024 + j;
    float xr = S[so], xi = S[so + P_DIM];
    int base = chunk * RCH;
    int reo = dir ? (P_DIM + j) : j;
    int imo = reo + 1024;
    for (int i = 0; i < RCH; ++i) {
        int row = dir ? (base + RCH - 1 - i) : (base + i);
        float br = bf2f(Bu[(size_t)row * 1024 + j]);
        float bi = bf2f(Bu[(size_t)row * 1024 + P_DIM + j]);
        float nr = fmaf(ar, xr, fmaf(-ai, xi, br));
        float ni = fmaf(ar, xi, fmaf( ai, xr, bi));
        xr = nr; xi = ni;
        XS[(size_t)row * 2048 + reo] = (short)f2bf(xr);
        XS[(size_t)row * 2048 + imo] = (short)f2bf(xi);
    }
}

// ---------------- 256x256 GEMM, m201 4-phase skeleton ----------------
// A (M,K) bf16 rm; Bm (N,K) bf16 rm.  OUT=0: bf16 store. OUT=1: f32 + Dv[c]*U[r,c].
// LDS: 2 bufs x {A,B} x {kh0,kh1} x 16KB.  Stages: s0=A(kh0) s1=B(kh0) s2=A(kh1) s3=B(kh1)
// of tile t+1 issued at phases P0..P3 of tile t.  vmcnt(4)=2 stages at P1,P3:
//   P3(t-1) proves s0(t),s1(t) (read P0/P1 tops of t, two barriers later);
//   P1(t)   proves s2(t),s3(t) (read P2/P3 tops).
#define SUB(b,op,kh) (&lds[((((b)*2)+(op))*2+(kh))*8192])

#define LDB(base) do { const short* _p = (base); \
    b0 = *(const short8v*)&_p[roffB];        b1 = *(const short8v*)&_p[roffB + 512]; \
    b2 = *(const short8v*)&_p[roffB + 1024]; b3 = *(const short8v*)&_p[roffB + 1536]; } while (0)
#define LDAL(base) do { const short* _p = (base); \
    aL0 = *(const short8v*)&_p[roffA];        aL1 = *(const short8v*)&_p[roffA + 512]; \
    aL2 = *(const short8v*)&_p[roffA + 1024]; aL3 = *(const short8v*)&_p[roffA + 1536]; } while (0)
#define LDAH(base) do { const short* _p = (base); \
    aH0 = *(const short8v*)&_p[roffA + 2048]; aH1 = *(const short8v*)&_p[roffA + 2560]; \
    aH2 = *(const short8v*)&_p[roffA + 3072]; aH3 = *(const short8v*)&_p[roffA + 3584]; } while (0)

#define MF4(mi, a) \
    acc[mi][0] = __builtin_amdgcn_mfma_f32_16x16x32_bf16(a, b0, acc[mi][0], 0,0,0); \
    acc[mi][1] = __builtin_amdgcn_mfma_f32_16x16x32_bf16(a, b1, acc[mi][1], 0,0,0); \
    acc[mi][2] = __builtin_amdgcn_mfma_f32_16x16x32_bf16(a, b2, acc[mi][2], 0,0,0); \
    acc[mi][3] = __builtin_amdgcn_mfma_f32_16x16x32_bf16(a, b3, acc[mi][3], 0,0,0);

#define MFMA16L do { __builtin_amdgcn_s_setprio(1); \
    MF4(0, aL0) MF4(1, aL1) MF4(2, aL2) MF4(3, aL3) \
    __builtin_amdgcn_s_setprio(0); } while (0)
#define MFMA16H do { __builtin_amdgcn_s_setprio(1); \
    MF4(4, aH0) MF4(5, aH1) MF4(6, aH2) MF4(7, aH3) \
    __builtin_amdgcn_s_setprio(0); } while (0)

template<int M, int N, int K, int OUT>
__global__ __launch_bounds__(512, 2) void gemm4p(
    const short* __restrict__ A, const short* __restrict__ Bm, void* __restrict__ Co,
    const float* __restrict__ Dv, const float* __restrict__ U)
{
    __shared__ __align__(16) short lds[65536];   // 128 KiB
    constexpr int NTN = N / 256;
    constexpr int nwg = (M / 256) * NTN;
    constexpr int NT  = K / 64;
    static_assert(nwg % 8 == 0, "bijective XCD swizzle");

    int tid = threadIdx.x;
    int wave = tid >> 6, lane = tid & 63;
    int bid = blockIdx.x;
    int wg  = (bid & 7) * (nwg / 8) + (bid >> 3);
    int m0 = (wg / NTN) * 256, n0 = (wg % NTN) * 256;
    int wm = (wave >> 2) * 128, wn = (wave & 3) * 64;
    int lr = lane & 15;
    // bank swizzle: 16B phys slot = logical ^ ((row>>1)&3); row bits 1-2 == lane bits 1-2
    int sA = (lane >> 4) ^ ((lane >> 1) & 3);
    int roffA = (wm + lr) * 32 + sA * 8;
    int roffB = (wn + lr) * 32 + sA * 8;

    const short* Ag = A  + (size_t)m0 * K;
    const short* Bg = Bm + (size_t)n0 * K;

    // per-thread stage addresses (pre-swizzled global source, linear LDS dest)
    int sl0 = tid, sl1 = 512 + tid;
    size_t ga0 = (size_t)(sl0 >> 2) * K + (size_t)((((sl0 & 3) ^ ((sl0 >> 3) & 3))) * 8);
    size_t ga1 = (size_t)(sl1 >> 2) * K + (size_t)((((sl1 & 3) ^ ((sl1 >> 3) & 3))) * 8);
    int ld0 = sl0 * 8, ld1 = sl1 * 8;

    f32x4 acc[8][4];
#pragma unroll
    for (int m = 0; m < 8; ++m)
#pragma unroll
        for (int n = 0; n < 4; ++n) acc[m][n] = (f32x4){0.f, 0.f, 0.f, 0.f};

#define STAGE(G, k0, sb) do { short* _s = (sb); \
        GLD16((G) + ga0 + (k0), &_s[ld0]); \
        GLD16((G) + ga1 + (k0), &_s[ld1]); } while (0)

    // prologue: tile 0 (4 stages = 8 gld), prove s0,s1 for all waves
    STAGE(Ag, 0,  SUB(0,0,0));
    STAGE(Bg, 0,  SUB(0,1,0));
    STAGE(Ag, 32, SUB(0,0,1));
    STAGE(Bg, 32, SUB(0,1,1));
    VMCNT4;
    BARRIER;

    short8v aL0, aL1, aL2, aL3, aH0, aH1, aH2, aH3, b0, b1, b2, b3;

    for (int t = 0; t < NT; ++t) {
        int b = t & 1, nb = b ^ 1;
        int kn = ((t + 1 < NT) ? (t + 1) : 0) * 64;   // wrap: dummy tail stages keep counts
        const short* Ab0 = SUB(b,0,0); const short* Ab1 = SUB(b,0,1);
        const short* Bb0 = SUB(b,1,0); const short* Bb1 = SUB(b,1,1);

        // P0: reads B(kh0)+A-lo(kh0); stage s0(t+1); MFMA C-lo x kh0
        LDB(Bb0); LDAL(Ab0);
        STAGE(Ag, kn, SUB(nb,0,0));
        BARRIER;
        LGKM0;
        MFMA16L;
        BARRIER;

        // P1: reads A-hi(kh0); stage s1(t+1); vmcnt proves s2(t),s3(t); MFMA C-hi x kh0
        LDAH(Ab0);
        STAGE(Bg, kn, SUB(nb,1,0));
        VMCNT4;
        BARRIER;
        LGKM0;
        MFMA16H;
        BARRIER;

        // P2: reads B(kh1)+A-lo(kh1); stage s2(t+1); MFMA C-lo x kh1
        LDB(Bb1); LDAL(Ab1);
        STAGE(Ag, kn + 32, SUB(nb,0,1));
        BARRIER;
        LGKM0;
        MFMA16L;
        BARRIER;

        // P3: reads A-hi(kh1); stage s3(t+1); vmcnt proves s0(t+1),s1(t+1); MFMA C-hi x kh1
        LDAH(Ab1);
        STAGE(Bg, kn + 32, SUB(nb,1,1));
        VMCNT4;
        BARRIER;
        LGKM0;
        MFMA16H;
        BARRIER;
    }
    VMCNT0;   // drain dummy tail stages

    int lr4 = (lane >> 4) * 4;
#pragma unroll
    for (int m = 0; m < 8; ++m)
#pragma unroll
        for (int n = 0; n < 4; ++n) {
            int r = m0 + wm + m * 16 + lr4;
            int c = n0 + wn + n * 16 + lr;
#pragma unroll
            for (int i = 0; i < 4; ++i) {
                float v = acc[m][n][i];
                if constexpr (OUT == 1) {
                    v = fmaf(Dv[c], U[(size_t)(r + i) * N + c], v);
                    ((float*)Co)[(size_t)(r + i) * N + c] = v;
                } else {
                    ((short*)Co)[(size_t)(r + i) * N + c] = (short)f2bf(v);
                }
            }
        }
#undef STAGE
}

// ---------------- launch ----------------

extern "C" void kernel_launch(void* const* d_in, const int* in_sizes, int n_in,
                              void* d_out, int out_size, void* d_ws, size_t ws_size,
                              hipStream_t stream) {
    const float* u     = (const float*)d_in[0];
    const float* Lre   = (const float*)d_in[1];
    const float* Lim   = (const float*)d_in[2];
    const float* B_ri  = (const float*)d_in[3];
    const float* C_ri  = (const float*)d_in[4];
    const float* Dv    = (const float*)d_in[5];
    const float* lstep = (const float*)d_in[6];
    float* out = (float*)d_out;

    char* w = (char*)d_ws;
    short* u_bf = (short*)(w);                       // 32MB  [0,32)
    short* XS   = (short*)(w);                       // 64MB  [0,64) (after GEMM1 done)
    float* Gseg = (float*)(w + (33ull  << 20));      // 128KB (inside XS region, dead before phase_c)
    float* Tseg = (float*)(w + (34ull  << 20));      // 128KB (ditto)
    short* Bcat = (short*)(w + (64ull  << 20));      // 2MB
    short* Bu   = (short*)(w + (66ull  << 20));      // 32MB bf16
    short* Ccat = (short*)(w + (130ull << 20));      // 4MB
    float* E    = (float*)(w + (134ull << 20));      // 2MB
    float* Scar = (float*)(w + (136ull << 20));      // 2MB

    // 1. prep
    conv_u<<<(L_SEQ * H_DIM) / (256 * 8), 256, 0, stream>>>(u, u_bf);
    prep_B<<<(P_DIM * H_DIM) / (256 * 4), 256, 0, stream>>>(B_ri, Bcat, Lre, Lim, lstep);
    prep_C<<<(H_DIM * 1024) / (256 * 4), 256, 0, stream>>>(C_ri, Ccat);

    // 2. GEMM1: Bu(bf16) = u @ Bcat^T   (M=L, N=1024, K=H) -> 256 wgs
    gemm4p<L_SEQ, 1024, H_DIM, 0><<<(L_SEQ / 256) * (1024 / 256), 512, 0, stream>>>(
        u_bf, Bcat, Bu, nullptr, nullptr);

    // 3. scans
    scan_phase_a<<<NCH, P_DIM, 0, stream>>>(Bu, E, Lre, Lim, lstep);
    carry_seg<<<dim3(16, 2), P_DIM, 0, stream>>>(E, Gseg, Lre, Lim, lstep);
    carry_mid<<<2, P_DIM, 0, stream>>>(Gseg, Tseg, Lre, Lim, lstep);
    carry_exp<<<dim3(16, 2), P_DIM, 0, stream>>>(E, Tseg, Scar, Lre, Lim, lstep);
    scan_phase_c<<<dim3(NCH, 2), P_DIM, 0, stream>>>(Bu, Scar, XS, Lre, Lim, lstep);

    // 4. GEMM2: out = XS @ Ccat^T + D*u   (M=L, N=H, K=2048) -> 256 wgs
    gemm4p<L_SEQ, H_DIM, 2048, 1><<<(L_SEQ / 256) * (H_DIM / 256), 512, 0, stream>>>(
        XS, Ccat, out, Dv, u);
}